// Round 1
// baseline (20410.579 us; speedup 1.0000x reference)
//
#include <hip/hip_runtime.h>
#include <hip/hip_bf16.h>

#define T_DIM 500
#define B_DIM 32
#define U_DIM 100
#define I_DIM 1024
#define E_DIM 512
#define M_DIM 512
#define CELL_DIM 1024
#define ODIM 512
#define NC 5000
#define G4 4096
#define KBODY 1536

typedef __attribute__((ext_vector_type(8))) short short8;
typedef __attribute__((ext_vector_type(4))) float f32x4;

__device__ __forceinline__ float bf2f(unsigned short u){
  union { unsigned int i; float f; } v; v.i = ((unsigned int)u) << 16; return v.f;
}
__device__ __forceinline__ unsigned short f2bf(float f){
  union { float f; unsigned int i; } v; v.f = f;
  unsigned int lsb = (v.i >> 16) & 1u;
  unsigned int r = v.i + 0x7fffu + lsb;
  return (unsigned short)(r >> 16);
}
__device__ __forceinline__ float fast_tanh(float x){
  float ax = fabsf(x);
  float e = __expf(2.0f * ax);
  float t = 1.0f - 2.0f / (e + 1.0f);
  return copysignf(t, x);
}
__device__ __forceinline__ float fast_sig(float x){
  return 1.0f / (1.0f + __expf(-x));
}

// ---------- precompute kernels ----------

__global__ void k_cvt_bf16(const float* __restrict__ src, unsigned short* __restrict__ dst, int n4){
  int i = blockIdx.x * 256 + threadIdx.x;
  if (i >= n4) return;
  float4 v = reinterpret_cast<const float4*>(src)[i];
  ushort4 o;
  o.x = f2bf(v.x); o.y = f2bf(v.y); o.z = f2bf(v.z); o.w = f2bf(v.w);
  reinterpret_cast<ushort4*>(dst)[i] = o;
}

__global__ void k_embed(const int* __restrict__ att_label, const float* __restrict__ emb_W,
                        float* __restrict__ embed){
  int idx = blockIdx.x * 256 + threadIdx.x;      // U*B*E
  int e  = idx & (E_DIM - 1);
  int ub = idx >> 9;
  int b  = ub & (B_DIM - 1);
  int u  = ub >> 5;
  int label = (u == 0) ? (NC - 2) : att_label[(u - 1) * B_DIM + b];
  float val = 0.0f;
  if (label >= 0) val = emb_W[label * E_DIM + e];
  embed[idx] = val;
}

__global__ void k_bias(const float* __restrict__ rnn_mask, float* __restrict__ bias){
  int idx = blockIdx.x * 256 + threadIdx.x;
  if (idx < T_DIM * B_DIM) bias[idx] = (rnn_mask[idx] - 1.0f) * 1e10f;
}

// Wcomb[m,c] = sum_o Wp2s[m,o] * Wproj[o,c]   (so state = h @ Wcomb^T)
__global__ void k_wcomb(const float* __restrict__ Wp2s, const float* __restrict__ Wproj,
                        float* __restrict__ Wcomb){
  int idx = blockIdx.x * 256 + threadIdx.x;   // 512*1024
  int c = idx & (CELL_DIM - 1);
  int m = idx >> 10;
  float acc = 0.f;
  for (int k = 0; k < ODIM; ++k)
    acc += Wp2s[m * ODIM + k] * Wproj[k * CELL_DIM + c];
  Wcomb[idx] = acc;
}

// att_h = data @ Wi2h^T : [16000,1024] x [512,1024]^T -> bf16 [16000,512]
__global__ __launch_bounds__(256) void k_atth(const unsigned short* __restrict__ A,
                                              const unsigned short* __restrict__ Bm,
                                              unsigned short* __restrict__ C){
  const int mt = blockIdx.x % 250;
  const int nt = blockIdx.x / 250;
  const int wave = threadIdx.x >> 6;
  const int lane = threadIdx.x & 63;
  const int r16 = lane & 15;
  const int kl = (lane >> 4) * 8;
  const unsigned short* aptr = A + (mt * 64 + wave * 16 + r16) * 1024 + kl;
  const unsigned short* bptr = Bm + (nt * 64 + r16) * 1024 + kl;
  f32x4 acc0 = {0,0,0,0}, acc1 = {0,0,0,0}, acc2 = {0,0,0,0}, acc3 = {0,0,0,0};
  for (int kk = 0; kk < 1024; kk += 32) {
    short8 a  = *reinterpret_cast<const short8*>(aptr + kk);
    short8 b0 = *reinterpret_cast<const short8*>(bptr + kk);
    short8 b1 = *reinterpret_cast<const short8*>(bptr + 16 * 1024 + kk);
    short8 b2 = *reinterpret_cast<const short8*>(bptr + 32 * 1024 + kk);
    short8 b3 = *reinterpret_cast<const short8*>(bptr + 48 * 1024 + kk);
    acc0 = __builtin_amdgcn_mfma_f32_16x16x32_bf16(a, b0, acc0, 0, 0, 0);
    acc1 = __builtin_amdgcn_mfma_f32_16x16x32_bf16(a, b1, acc1, 0, 0, 0);
    acc2 = __builtin_amdgcn_mfma_f32_16x16x32_bf16(a, b2, acc2, 0, 0, 0);
    acc3 = __builtin_amdgcn_mfma_f32_16x16x32_bf16(a, b3, acc3, 0, 0, 0);
  }
  const int orow = mt * 64 + wave * 16 + (lane >> 4) * 4;
  const int ocol = nt * 64 + r16;
  #pragma unroll
  for (int r = 0; r < 4; ++r) {
    C[(orow + r) * 512 + ocol]      = f2bf(acc0[r]);
    C[(orow + r) * 512 + ocol + 16] = f2bf(acc1[r]);
    C[(orow + r) * 512 + ocol + 32] = f2bf(acc2[r]);
    C[(orow + r) * 512 + ocol + 48] = f2bf(acc3[r]);
  }
}

// ---------- per-step kernels ----------

// gates[b,n] = b[n] + body[b,:]@Wx[n,:] + p[b,:]@Wp[n,:]   (body = [emb_u | ctx])
__global__ __launch_bounds__(256) void k_gates(const float* __restrict__ embed_u,
    const float* __restrict__ ctx, const float* __restrict__ pprev,
    const float* __restrict__ Wx, const float* __restrict__ Wp,
    const float* __restrict__ bvec, float* __restrict__ gates){
  __shared__ float s_x[32][140];
  const int tid = threadIdx.x;
  const int n = blockIdx.x * 8 + (tid & 7);
  const int b = tid >> 3;
  float acc = bvec[n];
  for (int ch = 0; ch < 12; ++ch) {           // body, 12 x 128 = 1536
    #pragma unroll
    for (int i = 0; i < 4; ++i) {
      int fidx = tid + i * 256;
      int bb = fidx >> 5;
      int kk4 = (fidx & 31) * 4;
      int k = ch * 128 + kk4;
      float4 v;
      if (k < 512) v = *reinterpret_cast<const float4*>(embed_u + bb * E_DIM + k);
      else         v = *reinterpret_cast<const float4*>(ctx + bb * I_DIM + (k - 512));
      *reinterpret_cast<float4*>(&s_x[bb][kk4]) = v;
    }
    __syncthreads();
    const float* wrow = Wx + n * KBODY + ch * 128;
    for (int kk = 0; kk < 128; kk += 4) {
      float4 xv = *reinterpret_cast<const float4*>(&s_x[b][kk]);
      float4 wv = *reinterpret_cast<const float4*>(wrow + kk);
      acc += xv.x * wv.x + xv.y * wv.y + xv.z * wv.z + xv.w * wv.w;
    }
    __syncthreads();
  }
  for (int ch = 0; ch < 4; ++ch) {            // p part, 4 x 128 = 512
    #pragma unroll
    for (int i = 0; i < 4; ++i) {
      int fidx = tid + i * 256;
      int bb = fidx >> 5;
      int kk4 = (fidx & 31) * 4;
      int k = ch * 128 + kk4;
      float4 v = *reinterpret_cast<const float4*>(pprev + bb * ODIM + k);
      *reinterpret_cast<float4*>(&s_x[bb][kk4]) = v;
    }
    __syncthreads();
    const float* wrow = Wp + n * ODIM + ch * 128;
    for (int kk = 0; kk < 128; kk += 4) {
      float4 xv = *reinterpret_cast<const float4*>(&s_x[b][kk]);
      float4 wv = *reinterpret_cast<const float4*>(wrow + kk);
      acc += xv.x * wv.x + xv.y * wv.y + xv.z * wv.z + xv.w * wv.w;
    }
    __syncthreads();
  }
  gates[b * G4 + n] = acc;
}

__global__ void k_cell(const float* __restrict__ gates, float* __restrict__ c_ws,
                       float* __restrict__ h_ws){
  int idx = blockIdx.x * 256 + threadIdx.x;   // 32*1024
  int b = idx >> 10;
  int j = idx & 1023;
  const float* g = gates + b * G4;
  float ig = fast_sig(g[j]);
  float fg = fast_sig(g[1024 + j]);
  float gg = fast_tanh(g[2048 + j]);
  float og = fast_sig(g[3072 + j]);
  float c = fg * c_ws[idx] + ig * gg;
  c = fminf(fmaxf(c, -1.0f), 1.0f);
  c_ws[idx] = c;
  h_ws[idx] = og * fast_tanh(c);
}

// p[b,o] = h@Wproj^T (n<512), state[b,m] = h@Wcomb^T (n>=512)
__global__ __launch_bounds__(256) void k_ps(const float* __restrict__ h_ws,
    const float* __restrict__ Wproj, const float* __restrict__ Wcomb,
    float* __restrict__ p_ws, float* __restrict__ state_ws,
    float* __restrict__ out, const float* __restrict__ att_mask, int u){
  __shared__ float s_h[32][140];
  const int tid = threadIdx.x;
  const int n = blockIdx.x * 8 + (tid & 7);   // 0..1023
  const int b = tid >> 3;
  float acc = 0.f;
  const float* wrow = (n < 512) ? (Wproj + n * CELL_DIM) : (Wcomb + (n - 512) * CELL_DIM);
  for (int ch = 0; ch < 8; ++ch) {
    #pragma unroll
    for (int i = 0; i < 4; ++i) {
      int fidx = tid + i * 256;
      int bb = fidx >> 5;
      int kk4 = (fidx & 31) * 4;
      float4 v = *reinterpret_cast<const float4*>(h_ws + bb * CELL_DIM + ch * 128 + kk4);
      *reinterpret_cast<float4*>(&s_h[bb][kk4]) = v;
    }
    __syncthreads();
    const float* w = wrow + ch * 128;
    for (int kk = 0; kk < 128; kk += 4) {
      float4 xv = *reinterpret_cast<const float4*>(&s_h[b][kk]);
      float4 wv = *reinterpret_cast<const float4*>(w + kk);
      acc += xv.x * wv.x + xv.y * wv.y + xv.z * wv.z + xv.w * wv.w;
    }
    __syncthreads();
  }
  if (n < 512) {
    p_ws[b * ODIM + n] = acc;
    out[(u * B_DIM + b) * 1536 + n] = acc * att_mask[u * B_DIM + b];
  } else {
    state_ws[b * M_DIM + (n - 512)] = acc;
  }
}

// scalar[t,b] = sigmoid(bias + sum_m w_v[m]*tanh(state[b,m]+att_h[t,b,m])); one wave per (t,b)
__global__ __launch_bounds__(256) void k_scalar(const unsigned short* __restrict__ att_h,
    const float* __restrict__ state_ws, const float* __restrict__ w_v,
    const float* __restrict__ bias, float* __restrict__ scal){
  const int lane = threadIdx.x & 63;
  const int tb = blockIdx.x * 4 + (threadIdx.x >> 6);
  const int b = tb & 31;
  const int m0 = lane * 8;
  const unsigned short* ap = att_h + tb * 512 + m0;
  ushort4 a0 = *reinterpret_cast<const ushort4*>(ap);
  ushort4 a1 = *reinterpret_cast<const ushort4*>(ap + 4);
  float4 s0 = *reinterpret_cast<const float4*>(state_ws + b * 512 + m0);
  float4 s1 = *reinterpret_cast<const float4*>(state_ws + b * 512 + m0 + 4);
  float4 w0 = *reinterpret_cast<const float4*>(w_v + m0);
  float4 w1 = *reinterpret_cast<const float4*>(w_v + m0 + 4);
  float acc = w0.x * fast_tanh(s0.x + bf2f(a0.x))
            + w0.y * fast_tanh(s0.y + bf2f(a0.y))
            + w0.z * fast_tanh(s0.z + bf2f(a0.z))
            + w0.w * fast_tanh(s0.w + bf2f(a0.w))
            + w1.x * fast_tanh(s1.x + bf2f(a1.x))
            + w1.y * fast_tanh(s1.y + bf2f(a1.y))
            + w1.z * fast_tanh(s1.z + bf2f(a1.z))
            + w1.w * fast_tanh(s1.w + bf2f(a1.w));
  #pragma unroll
  for (int off = 32; off >= 1; off >>= 1)
    acc += __shfl_xor(acc, off, 64);
  if (lane == 0)
    scal[tb] = fast_sig(acc + bias[tb]);
}

// ctx partials over 4 t-chunks of 125
__global__ __launch_bounds__(256) void k_ctx_part(const unsigned short* __restrict__ data_bf,
    const float* __restrict__ scal, float* __restrict__ part){
  __shared__ float s_s[128];
  const int tc = blockIdx.x >> 5;
  const int b = blockIdx.x & 31;
  const int tid = threadIdx.x;
  if (tid < 125) s_s[tid] = scal[(tc * 125 + tid) * B_DIM + b];
  __syncthreads();
  const int i0 = tid * 4;
  float4 acc = {0, 0, 0, 0};
  const unsigned short* dp = data_bf + ((size_t)(tc * 125 * B_DIM + b)) * I_DIM + i0;
  #pragma unroll 5
  for (int tt = 0; tt < 125; ++tt) {
    ushort4 v = *reinterpret_cast<const ushort4*>(dp);
    float s = s_s[tt];
    acc.x += bf2f(v.x) * s;
    acc.y += bf2f(v.y) * s;
    acc.z += bf2f(v.z) * s;
    acc.w += bf2f(v.w) * s;
    dp += B_DIM * I_DIM;
  }
  *reinterpret_cast<float4*>(part + (tc * B_DIM + b) * I_DIM + i0) = acc;
}

__global__ void k_ctx_final(const float* __restrict__ part, float* __restrict__ ctx,
    float* __restrict__ out, const float* __restrict__ att_mask, int u){
  int idx = blockIdx.x * 256 + threadIdx.x;   // 32*1024
  int b = idx >> 10;
  int i = idx & 1023;
  float v = part[idx] + part[32 * 1024 + idx] + part[2 * 32 * 1024 + idx] + part[3 * 32 * 1024 + idx];
  ctx[idx] = v;
  out[(u * B_DIM + b) * 1536 + 512 + i] = v * att_mask[u * B_DIM + b];
}

extern "C" void kernel_launch(void* const* d_in, const int* in_sizes, int n_in,
                              void* d_out, int out_size, void* d_ws, size_t ws_size,
                              hipStream_t stream) {
  const float* data     = (const float*)d_in[0];
  const float* att_mask = (const float*)d_in[1];
  const int*   att_label= (const int*)d_in[2];
  const float* rnn_mask = (const float*)d_in[3];
  const float* emb_W    = (const float*)d_in[4];
  const float* Wi2h     = (const float*)d_in[5];
  const float* Wp2s     = (const float*)d_in[6];
  const float* w_att_v  = (const float*)d_in[7];
  const float* Wx       = (const float*)d_in[8];
  const float* Wp       = (const float*)d_in[9];
  const float* bvec     = (const float*)d_in[10];
  const float* Wproj    = (const float*)d_in[11];
  float* out = (float*)d_out;

  char* ws = (char*)d_ws;
  size_t off = 0;
  auto alloc = [&](size_t bytes){ void* p = ws + off; off += (bytes + 255) & ~(size_t)255; return p; };
  unsigned short* data_bf = (unsigned short*)alloc((size_t)T_DIM * B_DIM * I_DIM * 2);
  unsigned short* atth_bf = (unsigned short*)alloc((size_t)T_DIM * B_DIM * M_DIM * 2);
  unsigned short* Wi2h_bf = (unsigned short*)alloc((size_t)M_DIM * I_DIM * 2);
  float* embed    = (float*)alloc((size_t)U_DIM * B_DIM * E_DIM * 4);
  float* bias     = (float*)alloc((size_t)T_DIM * B_DIM * 4);
  float* Wcomb    = (float*)alloc((size_t)M_DIM * CELL_DIM * 4);
  float* c_ws     = (float*)alloc((size_t)B_DIM * CELL_DIM * 4);
  float* h_ws     = (float*)alloc((size_t)B_DIM * CELL_DIM * 4);
  float* p_ws     = (float*)alloc((size_t)B_DIM * ODIM * 4);
  float* ctx_ws   = (float*)alloc((size_t)B_DIM * I_DIM * 4);
  float* state_ws = (float*)alloc((size_t)B_DIM * M_DIM * 4);
  float* gates    = (float*)alloc((size_t)B_DIM * G4 * 4);
  float* scal     = (float*)alloc((size_t)T_DIM * B_DIM * 4);
  float* part     = (float*)alloc((size_t)4 * B_DIM * I_DIM * 4);

  hipMemsetAsync(c_ws, 0, (size_t)B_DIM * CELL_DIM * 4, stream);
  hipMemsetAsync(p_ws, 0, (size_t)B_DIM * ODIM * 4, stream);
  hipMemsetAsync(ctx_ws, 0, (size_t)B_DIM * I_DIM * 4, stream);

  k_cvt_bf16<<<(T_DIM * B_DIM * I_DIM / 4 + 255) / 256, 256, 0, stream>>>(data, data_bf, T_DIM * B_DIM * I_DIM / 4);
  k_cvt_bf16<<<(M_DIM * I_DIM / 4 + 255) / 256, 256, 0, stream>>>(Wi2h, Wi2h_bf, M_DIM * I_DIM / 4);
  k_atth<<<2000, 256, 0, stream>>>(data_bf, Wi2h_bf, atth_bf);
  k_embed<<<U_DIM * B_DIM * E_DIM / 256, 256, 0, stream>>>(att_label, emb_W, embed);
  k_bias<<<(T_DIM * B_DIM + 255) / 256, 256, 0, stream>>>(rnn_mask, bias);
  k_wcomb<<<M_DIM * CELL_DIM / 256, 256, 0, stream>>>(Wp2s, Wproj, Wcomb);

  for (int u = 0; u < U_DIM; ++u) {
    k_gates<<<512, 256, 0, stream>>>(embed + (size_t)u * B_DIM * E_DIM, ctx_ws, p_ws, Wx, Wp, bvec, gates);
    k_cell<<<128, 256, 0, stream>>>(gates, c_ws, h_ws);
    k_ps<<<128, 256, 0, stream>>>(h_ws, Wproj, Wcomb, p_ws, state_ws, out, att_mask, u);
    k_scalar<<<4000, 256, 0, stream>>>(atth_bf, state_ws, w_att_v, bias, scal);
    k_ctx_part<<<128, 256, 0, stream>>>(data_bf, scal, part);
    k_ctx_final<<<128, 256, 0, stream>>>(part, ctx_ws, out, att_mask, u);
  }
}